// Round 7
// baseline (92.078 us; speedup 1.0000x reference)
//
#include <hip/hip_runtime.h>
#include <hip/hip_bf16.h>

#define SEQ 2048
#define DM  1024
#define NH  16
#define HD  64
#define BH  32
#define QB  64            // q rows per block (2 waves x 32)
#define KVB 64
#define NT  (SEQ/KVB)     // 32 tiles
#define TILE_E (KVB*HD)   // 4096 bf16 per tile

#define KWS_OFF 0u        // [BH][NT][64 key][64 d]  swizzle baked
#define VWS_OFF 4194304u  // [BH][NT][64 d][64 kv]   transposed, swizzle baked

typedef __bf16 bf16x8 __attribute__((ext_vector_type(8)));
typedef float  f32x16 __attribute__((ext_vector_type(16)));
typedef unsigned int u32;

#define LOG2E 1.44269504088896f

// ---- prep: K/V fp32 -> bf16 head-split tiles, V transposed, swizzle pre-baked ----
__global__ __launch_bounds__(256) void psa_prep(
    const float* __restrict__ V, const float* __restrict__ K,
    __bf16* __restrict__ ws)
{
    const int blk = blockIdx.x;
    if (blk < 2048) {
        // K chunk (bh, t, key, cb): K[b][t*64+key][h*64+d0..+7], d0=((cb^(key&7))<<3)
        const int idx = blk * 256 + threadIdx.x;
        const int cb = idx & 7, key = (idx >> 3) & 63, t = (idx >> 9) & 31, bh = idx >> 14;
        const int b = bh >> 4, h = bh & 15;
        const int d0 = ((cb ^ (key & 7)) << 3);
        const float* src = K + ((size_t)(b * SEQ + t * 64 + key)) * DM + h * HD + d0;
        float4 a = *(const float4*)src, c = *(const float4*)(src + 4);
        bf16x8 o;
        o[0] = (__bf16)a.x; o[1] = (__bf16)a.y; o[2] = (__bf16)a.z; o[3] = (__bf16)a.w;
        o[4] = (__bf16)c.x; o[5] = (__bf16)c.y; o[6] = (__bf16)c.z; o[7] = (__bf16)c.w;
        *(bf16x8*)(ws + KWS_OFF + (size_t)idx * 8) = o;
    } else {
        // V chunk (bh, t, d, cb): V[b][t*64+ks0+j][h*64+d], ks0=((cb^(d&7))<<3)
        const int idx = (blk - 2048) * 256 + threadIdx.x;
        const int cb = idx & 7, d = (idx >> 3) & 63, t = (idx >> 9) & 31, bh = idx >> 14;
        const int b = bh >> 4, h = bh & 15;
        const int ks0 = ((cb ^ (d & 7)) << 3);
        const float* src = V + ((size_t)(b * SEQ + t * 64 + ks0)) * DM + h * HD + d;
        bf16x8 o;
#pragma unroll
        for (int j = 0; j < 8; ++j) o[j] = (__bf16)src[(size_t)j * DM];
        *(bf16x8*)(ws + VWS_OFF + (size_t)idx * 8) = o;
    }
}

// ---- main: 2 waves x 32 q, 32x32x16 MFMA, in-register P via permlane32_swap ----
__global__ __launch_bounds__(128, 2) void psa_main(
    const __bf16* __restrict__ ws, const float* __restrict__ Qg,
    float* __restrict__ Og)
{
    __shared__ __bf16 KT[2][TILE_E];      // 8 KB x2
    __shared__ __bf16 VT[2][TILE_E];      // 8 KB x2

    const int bid = blockIdx.x;
    const int swz = (bid & 7) * 128 + (bid >> 3);   // XCD-aware; 1024 % 8 == 0
    const int bh  = swz >> 5;
    const int qb  = swz & 31;
    const int b   = bh >> 4, h = bh & 15;
    const int tid = threadIdx.x;
    const int w   = tid >> 6;
    const int l   = tid & 63;
    const int q32 = l & 31;
    const int hi  = l >> 5;
    const int q0  = qb * QB + w * 32;

    const __bf16* Kws = ws + KWS_OFF;
    const __bf16* Vws = ws + VWS_OFF;

    // Q B-frags: lane holds col q=q0+q32, k-dim d = st*16 + hi*8 + j
    bf16x8 qf[4];
#pragma unroll
    for (int st = 0; st < 4; ++st) {
        const float* p = Qg + ((size_t)b * SEQ + q0 + q32) * DM + h * HD + st * 16 + hi * 8;
        float4 a = *(const float4*)p, c = *(const float4*)(p + 4);
        bf16x8 o;
        o[0] = (__bf16)a.x; o[1] = (__bf16)a.y; o[2] = (__bf16)a.z; o[3] = (__bf16)a.w;
        o[4] = (__bf16)c.x; o[5] = (__bf16)c.y; o[6] = (__bf16)c.z; o[7] = (__bf16)c.w;
        qf[st] = o;
    }

    f32x16 accd[2];
    f32x16 z16;
#pragma unroll
    for (int r = 0; r < 16; ++r) { accd[0][r] = 0.f; accd[1][r] = 0.f; z16[r] = 0.f; }

    auto stage = [&](int bf, int t) {
        const size_t tb = ((size_t)bh * NT + t) * TILE_E;
#pragma unroll
        for (int i = 0; i < 4; ++i) {
            const int ch  = w * 4 + i;              // 8 x 1KB chunks per tensor
            const int off = ch * 512 + l * 8;
            __builtin_amdgcn_global_load_lds(
                (const __attribute__((address_space(1))) void*)(Kws + tb + off),
                (__attribute__((address_space(3))) void*)&KT[bf][ch * 512], 16, 0, 0);
            __builtin_amdgcn_global_load_lds(
                (const __attribute__((address_space(1))) void*)(Vws + tb + off),
                (__attribute__((address_space(3))) void*)&VT[bf][ch * 512], 16, 0, 0);
        }
    };

    stage(0, 0);

    for (int t = 0; t < NT; ++t) {
        const int cur = t & 1;
        if (t + 1 < NT) {
            stage(cur ^ 1, t + 1);                       // 8 loads stay in flight
            asm volatile("s_waitcnt vmcnt(8)" ::: "memory");
        } else {
            asm volatile("s_waitcnt vmcnt(0)" ::: "memory");
        }
        __builtin_amdgcn_s_barrier();                    // raw: no compiler drain
        __builtin_amdgcn_sched_barrier(0);

        // ---- QK^T (A=K, B=Q) -> silu -> in-register P frags (per 16-key step)
        u32 pw[4][4];
#pragma unroll
        for (int kb = 0; kb < 2; ++kb) {
            bf16x8 af[4];
#pragma unroll
            for (int st = 0; st < 4; ++st)
                af[st] = *(const bf16x8*)&KT[cur][(kb * 32 + q32) * 64 +
                          ((st * 16 + hi * 8) ^ ((q32 & 7) << 3))];
            __builtin_amdgcn_s_setprio(1);
            f32x16 s = __builtin_amdgcn_mfma_f32_32x32x16_bf16(af[0], qf[0], z16, 0, 0, 0);
            s = __builtin_amdgcn_mfma_f32_32x32x16_bf16(af[1], qf[1], s, 0, 0, 0);
            s = __builtin_amdgcn_mfma_f32_32x32x16_bf16(af[2], qf[2], s, 0, 0, 0);
            s = __builtin_amdgcn_mfma_f32_32x32x16_bf16(af[3], qf[3], s, 0, 0, 0);
            __builtin_amdgcn_s_setprio(0);
            float sl[16];
#pragma unroll
            for (int r = 0; r < 16; ++r) {
                float x = s[r];
                float e;
                asm("v_exp_f32 %0, %1" : "=v"(e) : "v"(x * -LOG2E));
                sl[r] = x * __builtin_amdgcn_rcpf(1.f + e);
            }
            // pack + cross-half exchange: frag words [A,C,B,D]
#pragma unroll
            for (int hf = 0; hf < 2; ++hf) {
                const int sb = hf * 8;
                u32 A, B, C, D;
                asm("v_cvt_pk_bf16_f32 %0, %1, %2" : "=v"(A) : "v"(sl[sb + 0]), "v"(sl[sb + 1]));
                asm("v_cvt_pk_bf16_f32 %0, %1, %2" : "=v"(B) : "v"(sl[sb + 4]), "v"(sl[sb + 5]));
                asm("v_cvt_pk_bf16_f32 %0, %1, %2" : "=v"(C) : "v"(sl[sb + 2]), "v"(sl[sb + 3]));
                asm("v_cvt_pk_bf16_f32 %0, %1, %2" : "=v"(D) : "v"(sl[sb + 6]), "v"(sl[sb + 7]));
                asm("v_permlane32_swap_b32 %0, %1" : "+v"(A), "+v"(B));
                asm("v_permlane32_swap_b32 %0, %1" : "+v"(C), "+v"(D));
                pw[kb * 2 + hf][0] = A; pw[kb * 2 + hf][1] = C;
                pw[kb * 2 + hf][2] = B; pw[kb * 2 + hf][3] = D;
            }
        }

        // ---- out += P * V  (A = P frags in regs, B = V from VT)
#pragma unroll
        for (int db = 0; db < 2; ++db) {
#pragma unroll
            for (int ks = 0; ks < 4; ++ks) {
                bf16x8 vf = *(const bf16x8*)&VT[cur][(db * 32 + q32) * 64 +
                             ((ks * 16 + hi * 8) ^ ((q32 & 7) << 3))];
                union { u32 u[4]; bf16x8 v; } pu;
                pu.u[0] = pw[ks][0]; pu.u[1] = pw[ks][1];
                pu.u[2] = pw[ks][2]; pu.u[3] = pw[ks][3];
                __builtin_amdgcn_s_setprio(1);
                accd[db] = __builtin_amdgcn_mfma_f32_32x32x16_bf16(pu.v, vf, accd[db], 0, 0, 0);
                __builtin_amdgcn_s_setprio(0);
            }
        }

        __builtin_amdgcn_sched_barrier(0);
        __builtin_amdgcn_s_barrier();                    // partner done reading cur
    }

    // ---- epilogue: D row q = r + 8m + 4hi, col d = db*32 + q32 (coalesced)
    float* op = Og + ((size_t)b * SEQ + q0) * DM + h * HD;
#pragma unroll
    for (int db = 0; db < 2; ++db)
#pragma unroll
        for (int m = 0; m < 4; ++m)
#pragma unroll
            for (int r = 0; r < 4; ++r)
                op[(size_t)(m * 8 + r + hi * 4) * DM + db * 32 + q32] = accd[db][m * 4 + r];
}

extern "C" void kernel_launch(void* const* d_in, const int* in_sizes, int n_in,
                              void* d_out, int out_size, void* d_ws, size_t ws_size,
                              hipStream_t stream) {
    const float* v = (const float*)d_in[0];
    const float* k = (const float*)d_in[1];
    const float* q = (const float*)d_in[2];
    float* out = (float*)d_out;
    __bf16* ws = (__bf16*)d_ws;
    (void)in_sizes; (void)n_in; (void)out_size; (void)ws_size;

    psa_prep<<<dim3(4096), dim3(256), 0, stream>>>(v, k, ws);
    psa_main<<<dim3(BH * (SEQ / QB)), dim3(128), 0, stream>>>(ws, q, out);
}

// Round 8
// 79.012 us; speedup vs baseline: 1.1654x; 1.1654x over previous
//
#include <hip/hip_runtime.h>
#include <hip/hip_bf16.h>

#define SEQ 2048
#define DM  1024
#define NH  16
#define HD  64
#define BH  32
#define QB  64            // q rows per block; wave owns 32 (q-half) x 32-key (kv-half)
#define KVB 64
#define NT  (SEQ/KVB)     // 32 tiles
#define TILE_E (KVB*HD)   // 4096 bf16 per tile

#define KWS_OFF 0u        // [BH][NT][64 key][64 d]  swizzle baked
#define VWS_OFF 4194304u  // [BH][NT][64 d][64 kv]   transposed, swizzle baked

typedef __bf16 bf16x8 __attribute__((ext_vector_type(8)));
typedef float  f32x16 __attribute__((ext_vector_type(16)));
typedef unsigned int u32;

#define LOG2E 1.44269504088896f

// ---- prep: K/V fp32 -> bf16 head-split tiles, V transposed, swizzle pre-baked ----
__global__ __launch_bounds__(256) void psa_prep(
    const float* __restrict__ V, const float* __restrict__ K,
    __bf16* __restrict__ ws)
{
    const int blk = blockIdx.x;
    if (blk < 2048) {
        // K chunk (bh, t, key, cb): K[b][t*64+key][h*64+d0..+7], d0=((cb^(key&7))<<3)
        const int idx = blk * 256 + threadIdx.x;
        const int cb = idx & 7, key = (idx >> 3) & 63, t = (idx >> 9) & 31, bh = idx >> 14;
        const int b = bh >> 4, h = bh & 15;
        const int d0 = ((cb ^ (key & 7)) << 3);
        const float* src = K + ((size_t)(b * SEQ + t * 64 + key)) * DM + h * HD + d0;
        float4 a = *(const float4*)src, c = *(const float4*)(src + 4);
        bf16x8 o;
        o[0] = (__bf16)a.x; o[1] = (__bf16)a.y; o[2] = (__bf16)a.z; o[3] = (__bf16)a.w;
        o[4] = (__bf16)c.x; o[5] = (__bf16)c.y; o[6] = (__bf16)c.z; o[7] = (__bf16)c.w;
        *(bf16x8*)(ws + KWS_OFF + (size_t)idx * 8) = o;
    } else {
        // V chunk (bh, t, d, cb): V[b][t*64+ks0+j][h*64+d], ks0=((cb^(d&7))<<3)
        const int idx = (blk - 2048) * 256 + threadIdx.x;
        const int cb = idx & 7, d = (idx >> 3) & 63, t = (idx >> 9) & 31, bh = idx >> 14;
        const int b = bh >> 4, h = bh & 15;
        const int ks0 = ((cb ^ (d & 7)) << 3);
        const float* src = V + ((size_t)(b * SEQ + t * 64 + ks0)) * DM + h * HD + d;
        bf16x8 o;
#pragma unroll
        for (int j = 0; j < 8; ++j) o[j] = (__bf16)src[(size_t)j * DM];
        *(bf16x8*)(ws + VWS_OFF + (size_t)idx * 8) = o;
    }
}

// ---- main: 4 waves = (q-half x kv-half), 32x32x16 MFMA, in-register P,
//      KV-split doubles wave-parallelism; LDS reduction pairs (w, w^2) ----
__global__ __launch_bounds__(256, 4) void psa_main(
    const __bf16* __restrict__ ws, const float* __restrict__ Qg,
    float* __restrict__ Og)
{
    __shared__ __bf16 KT[2][TILE_E];      // 8 KB x2
    __shared__ __bf16 VT[2][TILE_E];      // 8 KB x2

    const int bid = blockIdx.x;
    const int swz = (bid & 7) * 128 + (bid >> 3);   // XCD-aware; 1024 % 8 == 0
    const int bh  = swz >> 5;
    const int qb  = swz & 31;
    const int b   = bh >> 4, h = bh & 15;
    const int tid = threadIdx.x;
    const int w   = tid >> 6;
    const int l   = tid & 63;
    const int q32 = l & 31;
    const int hi  = l >> 5;
    const int qh  = w & 1;                // q-half
    const int kvh = w >> 1;               // kv-half
    const int q0  = qb * QB + qh * 32;

    const __bf16* Kws = ws + KWS_OFF;
    const __bf16* Vws = ws + VWS_OFF;

    // Q B-frags: lane holds col q=q0+q32, k-dim d = st*16 + hi*8 + j
    bf16x8 qf[4];
#pragma unroll
    for (int st = 0; st < 4; ++st) {
        const float* p = Qg + ((size_t)b * SEQ + q0 + q32) * DM + h * HD + st * 16 + hi * 8;
        float4 a = *(const float4*)p, c = *(const float4*)(p + 4);
        bf16x8 o;
        o[0] = (__bf16)a.x; o[1] = (__bf16)a.y; o[2] = (__bf16)a.z; o[3] = (__bf16)a.w;
        o[4] = (__bf16)c.x; o[5] = (__bf16)c.y; o[6] = (__bf16)c.z; o[7] = (__bf16)c.w;
        qf[st] = o;
    }

    f32x16 accd[2];
    f32x16 z16;
#pragma unroll
    for (int r = 0; r < 16; ++r) { accd[0][r] = 0.f; accd[1][r] = 0.f; z16[r] = 0.f; }

    auto stage = [&](int bf, int t) {
        const size_t tb = ((size_t)bh * NT + t) * TILE_E;
#pragma unroll
        for (int i = 0; i < 2; ++i) {
            const int ch  = w * 2 + i;              // 8 x 1KB chunks per tensor
            const int off = ch * 512 + l * 8;
            __builtin_amdgcn_global_load_lds(
                (const __attribute__((address_space(1))) void*)(Kws + tb + off),
                (__attribute__((address_space(3))) void*)&KT[bf][ch * 512], 16, 0, 0);
            __builtin_amdgcn_global_load_lds(
                (const __attribute__((address_space(1))) void*)(Vws + tb + off),
                (__attribute__((address_space(3))) void*)&VT[bf][ch * 512], 16, 0, 0);
        }
    };

    stage(0, 0);

    const int krow = kvh * 32 + q32;      // this wave's K row (A-frag)
    for (int t = 0; t < NT; ++t) {
        const int cur = t & 1;
        if (t + 1 < NT) {
            stage(cur ^ 1, t + 1);                       // next tile stays in flight
            asm volatile("s_waitcnt vmcnt(4)" ::: "memory");
        } else {
            asm volatile("s_waitcnt vmcnt(0)" ::: "memory");
        }
        __builtin_amdgcn_s_barrier();                    // raw: no compiler drain
        __builtin_amdgcn_sched_barrier(0);

        // ---- QK^T (A=K half, B=Q half) -> silu -> in-register P frags
        bf16x8 af[4];
#pragma unroll
        for (int st = 0; st < 4; ++st)
            af[st] = *(const bf16x8*)&KT[cur][krow * 64 +
                      ((st * 16 + hi * 8) ^ ((q32 & 7) << 3))];
        __builtin_amdgcn_s_setprio(1);
        f32x16 s = __builtin_amdgcn_mfma_f32_32x32x16_bf16(af[0], qf[0], z16, 0, 0, 0);
        s = __builtin_amdgcn_mfma_f32_32x32x16_bf16(af[1], qf[1], s, 0, 0, 0);
        s = __builtin_amdgcn_mfma_f32_32x32x16_bf16(af[2], qf[2], s, 0, 0, 0);
        s = __builtin_amdgcn_mfma_f32_32x32x16_bf16(af[3], qf[3], s, 0, 0, 0);
        __builtin_amdgcn_s_setprio(0);

        float sl[16];
#pragma unroll
        for (int r = 0; r < 16; ++r) {
            float x = s[r];
            float e;
            asm("v_exp_f32 %0, %1" : "=v"(e) : "v"(x * -LOG2E));
            sl[r] = x * __builtin_amdgcn_rcpf(1.f + e);
        }
        // pack + cross-half exchange: per 16-key step, frag words [A,C,B,D]
        u32 pw[2][4];
#pragma unroll
        for (int hf = 0; hf < 2; ++hf) {
            const int sb = hf * 8;
            u32 A, B, C, D;
            asm("v_cvt_pk_bf16_f32 %0, %1, %2" : "=v"(A) : "v"(sl[sb + 0]), "v"(sl[sb + 1]));
            asm("v_cvt_pk_bf16_f32 %0, %1, %2" : "=v"(B) : "v"(sl[sb + 4]), "v"(sl[sb + 5]));
            asm("v_cvt_pk_bf16_f32 %0, %1, %2" : "=v"(C) : "v"(sl[sb + 2]), "v"(sl[sb + 3]));
            asm("v_cvt_pk_bf16_f32 %0, %1, %2" : "=v"(D) : "v"(sl[sb + 6]), "v"(sl[sb + 7]));
            asm("v_permlane32_swap_b32 %0, %1" : "+v"(A), "+v"(B));
            asm("v_permlane32_swap_b32 %0, %1" : "+v"(C), "+v"(D));
            pw[hf][0] = A; pw[hf][1] = C; pw[hf][2] = B; pw[hf][3] = D;
        }

        // ---- out += P * V  (A = P frags in regs, B = V half from VT)
#pragma unroll
        for (int db = 0; db < 2; ++db) {
            const int vrow = db * 32 + q32;
#pragma unroll
            for (int ks = 0; ks < 2; ++ks) {
                bf16x8 vf = *(const bf16x8*)&VT[cur][vrow * 64 +
                             ((kvh * 32 + ks * 16 + hi * 8) ^ ((vrow & 7) << 3))];
                union { u32 u[4]; bf16x8 v; } pu;
                pu.u[0] = pw[ks][0]; pu.u[1] = pw[ks][1];
                pu.u[2] = pw[ks][2]; pu.u[3] = pw[ks][3];
                __builtin_amdgcn_s_setprio(1);
                accd[db] = __builtin_amdgcn_mfma_f32_32x32x16_bf16(pu.v, vf, accd[db], 0, 0, 0);
                __builtin_amdgcn_s_setprio(0);
            }
        }

        __builtin_amdgcn_sched_barrier(0);
        __builtin_amdgcn_s_barrier();                    // all waves done reading cur
    }

    // ---- reduce kv-halves: waves 2,3 dump acc into KT region; waves 0,1 add+store
    float* red = (float*)&KT[0][0];                      // 16 KB, free now
    if (w >= 2) {
        const int slot = (qh * 64 + l) * 32;
#pragma unroll
        for (int db = 0; db < 2; ++db)
#pragma unroll
            for (int r = 0; r < 16; ++r)
                red[slot + db * 16 + r] = accd[db][r];
    }
    __syncthreads();
    if (w < 2) {
        const int slot = (qh * 64 + l) * 32;
#pragma unroll
        for (int db = 0; db < 2; ++db)
#pragma unroll
            for (int r = 0; r < 16; ++r)
                accd[db][r] += red[slot + db * 16 + r];
        // D layout: row q = m*8 + r + hi*4, col d = db*32 + q32 (coalesced)
        float* op = Og + ((size_t)b * SEQ + q0) * DM + h * HD;
#pragma unroll
        for (int db = 0; db < 2; ++db)
#pragma unroll
            for (int m = 0; m < 4; ++m)
#pragma unroll
                for (int r = 0; r < 4; ++r)
                    op[(size_t)(m * 8 + r + hi * 4) * DM + db * 32 + q32] = accd[db][m * 4 + r];
    }
}

extern "C" void kernel_launch(void* const* d_in, const int* in_sizes, int n_in,
                              void* d_out, int out_size, void* d_ws, size_t ws_size,
                              hipStream_t stream) {
    const float* v = (const float*)d_in[0];
    const float* k = (const float*)d_in[1];
    const float* q = (const float*)d_in[2];
    float* out = (float*)d_out;
    __bf16* ws = (__bf16*)d_ws;
    (void)in_sizes; (void)n_in; (void)out_size; (void)ws_size;

    psa_prep<<<dim3(4096), dim3(256), 0, stream>>>(v, k, ws);
    psa_main<<<dim3(BH * (SEQ / QB)), dim3(256), 0, stream>>>(ws, q, out);
}